// Round 8
// baseline (96.372 us; speedup 1.0000x reference)
//
#include <hip/hip_runtime.h>
#include <hip/hip_fp16.h>

#define N_CLASS_C 6
#define MAX_WORDS 33344          // cell-table words; supports n_atoms <= 100,032
#define FILTER_BLOCK 1024
#define FILTER_GRID 256

typedef int vint2 __attribute__((ext_vector_type(2)));

// 8-byte packed atom record: fp16 x,y,z,radius. One dwordx2 gather per atom.
struct alignas(8) HAtom {
    __half x, y, z, r;
};

// ---------------- ws layout ----------------
// [0..24)   : accum[6]
// [24..28)  : ticket (unsigned)
// [256..)   : HAtom table
// then      : packed cell words

__global__ void zero_hdr(float* accum, unsigned* ticket) {
    if (threadIdx.x < N_CLASS_C) accum[threadIdx.x] = 0.0f;
    if (threadIdx.x == 0) *ticket = 0u;
}

// Fused prep: per-block redundant w-reduce (radii max, tol max), then per
// word t: pack 3 atoms' HAtom records + 10-bit cell ids.
// cell id: cx(3b) | cy(3b)<<3 | cz(4b)<<6; clamped -> false positives only.
__global__ __launch_bounds__(256) void prep(
    const float* __restrict__ coords,
    const float* __restrict__ radii,
    const int* __restrict__ names,
    const float* __restrict__ tol,
    int n_radii,
    HAtom* __restrict__ atoms,
    unsigned* __restrict__ cellsg,
    int n_words, int n_atoms) {
    __shared__ float sh[4];
    __shared__ float shw;
    {
        float m = 0.0f;
        for (int i = threadIdx.x; i < n_radii; i += blockDim.x)
            m = fmaxf(m, radii[i]);
#pragma unroll
        for (int off = 32; off > 0; off >>= 1) m = fmaxf(m, __shfl_down(m, off, 64));
        if ((threadIdx.x & 63) == 0) sh[threadIdx.x >> 6] = m;
        __syncthreads();
        if (threadIdx.x == 0) {
            float mm = fmaxf(fmaxf(sh[0], sh[1]), fmaxf(sh[2], sh[3]));
            float tmax = -1e30f;
            for (int c = 0; c < N_CLASS_C; ++c) tmax = fmaxf(tmax, tol[c]);
            // any clash has dist < 2*rmax + tmax; margin for strictness
            shw = fmaxf(2.0f * mm + tmax, 1e-2f) + 1e-3f;
        }
        __syncthreads();
    }
    float inv = 1.0f / shw;

    int t = blockIdx.x * blockDim.x + threadIdx.x;
    if (t < n_words) {
        unsigned word = 0;
#pragma unroll
        for (int s = 0; s < 3; ++s) {
            int i = 3 * t + s;
            unsigned c = 0;
            if (i < n_atoms) {
                float x = coords[3 * i + 0];
                float y = coords[3 * i + 1];
                float z = coords[3 * i + 2];
                HAtom a;
                a.x = __float2half(x);
                a.y = __float2half(y);
                a.z = __float2half(z);
                a.r = __float2half(radii[names[i]]);
                atoms[i] = a;
                int cx = (int)floorf(x * inv) + 4;
                int cy = (int)floorf(y * inv) + 4;
                int cz = (int)floorf(z * inv) + 8;
                cx = min(max(cx, 0), 7);
                cy = min(max(cy, 0), 7);
                cz = min(max(cz, 0), 15);
                c = (unsigned)cx | ((unsigned)cy << 3) | ((unsigned)cz << 6);
            }
            word |= c << (10 * s);
        }
        cellsg[t] = word;
    }
}

__device__ __forceinline__ unsigned cell_lookup(const unsigned* cells, int i) {
    // q = i / 3 (u32-safe magic), r = i % 3
    unsigned q = (unsigned)(((unsigned long long)(unsigned)i * 0xAAAAAAABull) >> 33);
    unsigned r = (unsigned)i - 3u * q;
    return (cells[q] >> (10u * r)) & 0x3FFu;
}

__device__ __forceinline__ void block_reduce_accum(float* s, float* accum) {
    __shared__ float sh[N_CLASS_C];
    if (threadIdx.x < N_CLASS_C) sh[threadIdx.x] = 0.0f;
    __syncthreads();
#pragma unroll
    for (int c = 0; c < N_CLASS_C; ++c) {
        float v = s[c];
#pragma unroll
        for (int off = 32; off > 0; off >>= 1) v += __shfl_down(v, off, 64);
        if ((threadIdx.x & 63) == 0 && v != 0.0f) atomicAdd(&sh[c], v);
    }
    __syncthreads();
    if (threadIdx.x < N_CLASS_C) {
        float v = sh[threadIdx.x];
        if (v != 0.0f) atomicAdd(&accum[threadIdx.x], v);
    }
}

__device__ __forceinline__ float hdist_base(const HAtom& A, const HAtom& B) {
    float dx = __half2float(A.x) - __half2float(B.x);
    float dy = __half2float(A.y) - __half2float(B.y);
    float dz = __half2float(A.z) - __half2float(B.z);
    float dist = sqrtf(dx * dx + dy * dy + dz * dz + 1e-12f);
    return (__half2float(A.r) + __half2float(B.r)) - dist;
}

// Main kernel: LDS-resident cell table filters pairs without any VMEM
// request; only ~5% of pairs issue the 2 scattered atom gathers.
// Last block (ticket) applies exp(weight) and writes d_out.
__global__ __launch_bounds__(FILTER_BLOCK) void clash_filtered(
    const int* __restrict__ pairs,        // 2 * n_pairs
    const HAtom* __restrict__ atoms,
    const unsigned* __restrict__ cellsg,  // n_words packed cells
    const int* __restrict__ masks,        // N_CLASS * n_pairs
    const float* __restrict__ tol,
    const float* __restrict__ weight,
    float* __restrict__ accum,
    unsigned* __restrict__ ticket,
    float* __restrict__ out,
    int n_pairs, int n_words, int nblocks) {
    __shared__ unsigned cells[MAX_WORDS];
    for (int i = threadIdx.x; i < n_words; i += FILTER_BLOCK)
        cells[i] = cellsg[i];

    float tc[N_CLASS_C];
#pragma unroll
    for (int c = 0; c < N_CLASS_C; ++c) tc[c] = tol[c];
    float tmax = tc[0];
#pragma unroll
    for (int c = 1; c < N_CLASS_C; ++c) tmax = fmaxf(tmax, tc[c]);

    float s[N_CLASS_C];
#pragma unroll
    for (int c = 0; c < N_CLASS_C; ++c) s[c] = 0.0f;

    __syncthreads();

    const vint2* pairs2 = reinterpret_cast<const vint2*>(pairs);
    const int stride = gridDim.x * FILTER_BLOCK;
    for (int p = blockIdx.x * FILTER_BLOCK + threadIdx.x; p < n_pairs; p += stride) {
        vint2 pr = __builtin_nontemporal_load(&pairs2[p]);
        unsigned ca = cell_lookup(cells, pr.x);
        unsigned cb = cell_lookup(cells, pr.y);
        int dx = abs((int)(ca & 7u) - (int)(cb & 7u));
        int dy = abs((int)((ca >> 3) & 7u) - (int)((cb >> 3) & 7u));
        int dz = abs((int)((ca >> 6) & 15u) - (int)((cb >> 6) & 15u));
        // all non-negative: (dx|dy|dz) <= 1  <=>  dx<=1 && dy<=1 && dz<=1
        if ((dx | dy | dz) <= 1) {
            HAtom A = atoms[pr.x];
            HAtom B = atoms[pr.y];
            float base = hdist_base(A, B);
            if (base + tmax > 0.0f) {
#pragma unroll
                for (int c = 0; c < N_CLASS_C; ++c) {
                    if (__builtin_nontemporal_load(&masks[(size_t)c * n_pairs + p]))
                        s[c] += fmaxf(base + tc[c], 0.0f);
                }
            }
        }
    }

    block_reduce_accum(s, accum);

    // ---- fused finalize: last block scales and writes out ----
    __threadfence();            // make this thread's atomics visible device-wide
    __syncthreads();            // all threads in block have fenced
    __shared__ int last;
    if (threadIdx.x == 0) {
        unsigned tk = atomicAdd(ticket, 1u);
        last = (tk == (unsigned)(nblocks - 1)) ? 1 : 0;
    }
    __syncthreads();
    if (last && threadIdx.x < N_CLASS_C) {
        __threadfence();
        float v = atomicAdd(&accum[threadIdx.x], 0.0f);  // coherent read
        out[threadIdx.x] = v * expf(weight[0]);
    }
}

// -------- fallback (tiny ws / oversized atom count): direct gather path --------
__global__ void zero_accum_fb(float* accum) {
    if (threadIdx.x < N_CLASS_C) accum[threadIdx.x] = 0.0f;
}

__global__ __launch_bounds__(256) void clash_fallback(
    const int* __restrict__ pairs,
    const float* __restrict__ coords,
    const float* __restrict__ radii,
    const int* __restrict__ names,
    const int* __restrict__ masks,
    const float* __restrict__ tol,
    float* __restrict__ accum,
    int n_pairs) {
    float tc[N_CLASS_C];
#pragma unroll
    for (int c = 0; c < N_CLASS_C; ++c) tc[c] = tol[c];
    float tmax = tc[0];
#pragma unroll
    for (int c = 1; c < N_CLASS_C; ++c) tmax = fmaxf(tmax, tc[c]);
    float s[N_CLASS_C];
#pragma unroll
    for (int c = 0; c < N_CLASS_C; ++c) s[c] = 0.0f;

    const int tid = blockIdx.x * blockDim.x + threadIdx.x;
    const int stride = gridDim.x * blockDim.x;
    for (int p = tid; p < n_pairs; p += stride) {
        int a0 = pairs[2 * p], a1 = pairs[2 * p + 1];
        float dx = coords[3 * a0] - coords[3 * a1];
        float dy = coords[3 * a0 + 1] - coords[3 * a1 + 1];
        float dz = coords[3 * a0 + 2] - coords[3 * a1 + 2];
        float dist = sqrtf(dx * dx + dy * dy + dz * dz + 1e-12f);
        float base = (radii[names[a0]] + radii[names[a1]]) - dist;
        if (base + tmax > 0.0f) {
#pragma unroll
            for (int c = 0; c < N_CLASS_C; ++c) {
                if (masks[(size_t)c * n_pairs + p])
                    s[c] += fmaxf(base + tc[c], 0.0f);
            }
        }
    }
    block_reduce_accum(s, accum);
}

__global__ void finalize_fb(const float* __restrict__ accum,
                            const float* __restrict__ w,
                            float* __restrict__ out) {
    int c = threadIdx.x;
    if (c < N_CLASS_C) {
        float scale = expf(w[0]);
        out[c] = accum[c] * scale;
    }
}

extern "C" void kernel_launch(void* const* d_in, const int* in_sizes, int n_in,
                              void* d_out, int out_size, void* d_ws, size_t ws_size,
                              hipStream_t stream) {
    const float* coords = (const float*)d_in[0];
    const float* radii  = (const float*)d_in[1];
    const float* tol    = (const float*)d_in[2];
    const float* weight = (const float*)d_in[3];
    const int* names    = (const int*)d_in[4];
    const int* pairs    = (const int*)d_in[5];
    const int* masks    = (const int*)d_in[6];
    float* out = (float*)d_out;

    int n_atoms = in_sizes[4];
    int n_radii = in_sizes[1];
    int n_pairs = in_sizes[5] / 2;

    int n_words = (n_atoms + 2) / 3;
    size_t atoms_off = 256;
    size_t atoms_bytes = (size_t)n_atoms * sizeof(HAtom);
    size_t cells_off = (atoms_off + atoms_bytes + 255) & ~(size_t)255;
    size_t need = cells_off + (size_t)n_words * 4 + 64;

    if (ws_size >= need && n_words <= MAX_WORDS) {
        float* accum = (float*)d_ws;                       // 6 floats
        unsigned* ticket = (unsigned*)((char*)d_ws + 24);
        HAtom* atoms = (HAtom*)((char*)d_ws + atoms_off);
        unsigned* cellsg = (unsigned*)((char*)d_ws + cells_off);

        zero_hdr<<<1, 64, 0, stream>>>(accum, ticket);
        prep<<<(n_words + 255) / 256, 256, 0, stream>>>(coords, radii, names, tol,
                                                        n_radii, atoms, cellsg,
                                                        n_words, n_atoms);
        clash_filtered<<<FILTER_GRID, FILTER_BLOCK, 0, stream>>>(
            pairs, atoms, cellsg, masks, tol, weight, accum, ticket, out,
            n_pairs, n_words, FILTER_GRID);
    } else {
        float* accum = out;
        zero_accum_fb<<<1, 64, 0, stream>>>(accum);
        clash_fallback<<<2048, 256, 0, stream>>>(pairs, coords, radii, names,
                                                 masks, tol, accum, n_pairs);
        finalize_fb<<<1, 64, 0, stream>>>(accum, weight, out);
    }
}

// Round 9
// 93.791 us; speedup vs baseline: 1.0275x; 1.0275x over previous
//
#include <hip/hip_runtime.h>
#include <hip/hip_fp16.h>

#define N_CLASS_C 6
#define MAX_WORDS 33344          // cell-table words; supports n_atoms <= 100,032
#define FILTER_BLOCK 1024
#define FILTER_GRID 256

typedef int vint2 __attribute__((ext_vector_type(2)));

// 8-byte packed atom record: fp16 x,y,z,radius. One dwordx2 gather per atom.
struct alignas(8) HAtom {
    __half x, y, z, r;
};

// ---------------- ws layout ----------------
// [0..24)   : accum[6]
// [24..28)  : ticket (unsigned)
// [256..)   : HAtom table
// then      : packed cell words

__global__ void zero_hdr(float* accum, unsigned* ticket) {
    if (threadIdx.x < N_CLASS_C) accum[threadIdx.x] = 0.0f;
    if (threadIdx.x == 0) *ticket = 0u;
}

// Fused prep: per-block redundant w-reduce (radii max, tol max), then per
// word t: pack 3 atoms' HAtom records + 10-bit cell ids.
// cell id: cx(3b) | cy(3b)<<3 | cz(4b)<<6; clamped -> false positives only.
__global__ __launch_bounds__(256) void prep(
    const float* __restrict__ coords,
    const float* __restrict__ radii,
    const int* __restrict__ names,
    const float* __restrict__ tol,
    int n_radii,
    HAtom* __restrict__ atoms,
    unsigned* __restrict__ cellsg,
    int n_words, int n_atoms) {
    __shared__ float sh[4];
    __shared__ float shw;
    {
        float m = 0.0f;
        for (int i = threadIdx.x; i < n_radii; i += blockDim.x)
            m = fmaxf(m, radii[i]);
#pragma unroll
        for (int off = 32; off > 0; off >>= 1) m = fmaxf(m, __shfl_down(m, off, 64));
        if ((threadIdx.x & 63) == 0) sh[threadIdx.x >> 6] = m;
        __syncthreads();
        if (threadIdx.x == 0) {
            float mm = fmaxf(fmaxf(sh[0], sh[1]), fmaxf(sh[2], sh[3]));
            float tmax = -1e30f;
            for (int c = 0; c < N_CLASS_C; ++c) tmax = fmaxf(tmax, tol[c]);
            // any clash has dist < 2*rmax + tmax; margin for strictness
            shw = fmaxf(2.0f * mm + tmax, 1e-2f) + 1e-3f;
        }
        __syncthreads();
    }
    float inv = 1.0f / shw;

    int t = blockIdx.x * blockDim.x + threadIdx.x;
    if (t < n_words) {
        unsigned word = 0;
#pragma unroll
        for (int s = 0; s < 3; ++s) {
            int i = 3 * t + s;
            unsigned c = 0;
            if (i < n_atoms) {
                float x = coords[3 * i + 0];
                float y = coords[3 * i + 1];
                float z = coords[3 * i + 2];
                HAtom a;
                a.x = __float2half(x);
                a.y = __float2half(y);
                a.z = __float2half(z);
                a.r = __float2half(radii[names[i]]);
                atoms[i] = a;
                int cx = (int)floorf(x * inv) + 4;
                int cy = (int)floorf(y * inv) + 4;
                int cz = (int)floorf(z * inv) + 8;
                cx = min(max(cx, 0), 7);
                cy = min(max(cy, 0), 7);
                cz = min(max(cz, 0), 15);
                c = (unsigned)cx | ((unsigned)cy << 3) | ((unsigned)cz << 6);
            }
            word |= c << (10 * s);
        }
        cellsg[t] = word;
    }
}

__device__ __forceinline__ unsigned cell_lookup(const unsigned* cells, int i) {
    // q = i / 3 (u32-safe magic), r = i % 3
    unsigned q = (unsigned)(((unsigned long long)(unsigned)i * 0xAAAAAAABull) >> 33);
    unsigned r = (unsigned)i - 3u * q;
    return (cells[q] >> (10u * r)) & 0x3FFu;
}

__device__ __forceinline__ void block_reduce_accum(float* s, float* accum) {
    __shared__ float sh[N_CLASS_C];
    if (threadIdx.x < N_CLASS_C) sh[threadIdx.x] = 0.0f;
    __syncthreads();
#pragma unroll
    for (int c = 0; c < N_CLASS_C; ++c) {
        float v = s[c];
#pragma unroll
        for (int off = 32; off > 0; off >>= 1) v += __shfl_down(v, off, 64);
        if ((threadIdx.x & 63) == 0 && v != 0.0f) atomicAdd(&sh[c], v);
    }
    __syncthreads();
    if (threadIdx.x < N_CLASS_C) {
        float v = sh[threadIdx.x];
        if (v != 0.0f) atomicAdd(&accum[threadIdx.x], v);
    }
}

__device__ __forceinline__ float hdist_base(const HAtom& A, const HAtom& B) {
    float dx = __half2float(A.x) - __half2float(B.x);
    float dy = __half2float(A.y) - __half2float(B.y);
    float dz = __half2float(A.z) - __half2float(B.z);
    float dist = sqrtf(dx * dx + dy * dy + dz * dz + 1e-12f);
    return (__half2float(A.r) + __half2float(B.r)) - dist;
}

// Main kernel: LDS-resident cell table filters pairs without any VMEM
// request; only the surviving pairs issue the 2 scattered atom gathers.
// Last block (ticket) applies exp(weight) and writes d_out.
// NOTE: plain loads everywhere — nontemporal hints on gfx950 measured 2-4x
// slower on these streams (rounds 3 and 8).
__global__ __launch_bounds__(FILTER_BLOCK) void clash_filtered(
    const int* __restrict__ pairs,        // 2 * n_pairs
    const HAtom* __restrict__ atoms,
    const unsigned* __restrict__ cellsg,  // n_words packed cells
    const int* __restrict__ masks,        // N_CLASS * n_pairs
    const float* __restrict__ tol,
    const float* __restrict__ weight,
    float* __restrict__ accum,
    unsigned* __restrict__ ticket,
    float* __restrict__ out,
    int n_pairs, int n_words, int nblocks) {
    __shared__ unsigned cells[MAX_WORDS];
    for (int i = threadIdx.x; i < n_words; i += FILTER_BLOCK)
        cells[i] = cellsg[i];

    float tc[N_CLASS_C];
#pragma unroll
    for (int c = 0; c < N_CLASS_C; ++c) tc[c] = tol[c];
    float tmax = tc[0];
#pragma unroll
    for (int c = 1; c < N_CLASS_C; ++c) tmax = fmaxf(tmax, tc[c]);

    float s[N_CLASS_C];
#pragma unroll
    for (int c = 0; c < N_CLASS_C; ++c) s[c] = 0.0f;

    __syncthreads();

    const vint2* pairs2 = reinterpret_cast<const vint2*>(pairs);
    const int stride = gridDim.x * FILTER_BLOCK;
    for (int p = blockIdx.x * FILTER_BLOCK + threadIdx.x; p < n_pairs; p += stride) {
        vint2 pr = pairs2[p];
        unsigned ca = cell_lookup(cells, pr.x);
        unsigned cb = cell_lookup(cells, pr.y);
        int dx = abs((int)(ca & 7u) - (int)(cb & 7u));
        int dy = abs((int)((ca >> 3) & 7u) - (int)((cb >> 3) & 7u));
        int dz = abs((int)((ca >> 6) & 15u) - (int)((cb >> 6) & 15u));
        // all non-negative: (dx|dy|dz) <= 1  <=>  dx<=1 && dy<=1 && dz<=1
        if ((dx | dy | dz) <= 1) {
            HAtom A = atoms[pr.x];
            HAtom B = atoms[pr.y];
            float base = hdist_base(A, B);
            if (base + tmax > 0.0f) {
#pragma unroll
                for (int c = 0; c < N_CLASS_C; ++c) {
                    if (masks[(size_t)c * n_pairs + p])
                        s[c] += fmaxf(base + tc[c], 0.0f);
                }
            }
        }
    }

    block_reduce_accum(s, accum);

    // ---- fused finalize: last block scales and writes out ----
    __threadfence();            // make this thread's atomics visible device-wide
    __syncthreads();            // all threads in block have fenced
    __shared__ int last;
    if (threadIdx.x == 0) {
        unsigned tk = atomicAdd(ticket, 1u);
        last = (tk == (unsigned)(nblocks - 1)) ? 1 : 0;
    }
    __syncthreads();
    if (last && threadIdx.x < N_CLASS_C) {
        __threadfence();
        float v = atomicAdd(&accum[threadIdx.x], 0.0f);  // coherent read
        out[threadIdx.x] = v * expf(weight[0]);
    }
}

// -------- fallback (tiny ws / oversized atom count): direct gather path --------
__global__ void zero_accum_fb(float* accum) {
    if (threadIdx.x < N_CLASS_C) accum[threadIdx.x] = 0.0f;
}

__global__ __launch_bounds__(256) void clash_fallback(
    const int* __restrict__ pairs,
    const float* __restrict__ coords,
    const float* __restrict__ radii,
    const int* __restrict__ names,
    const int* __restrict__ masks,
    const float* __restrict__ tol,
    float* __restrict__ accum,
    int n_pairs) {
    float tc[N_CLASS_C];
#pragma unroll
    for (int c = 0; c < N_CLASS_C; ++c) tc[c] = tol[c];
    float tmax = tc[0];
#pragma unroll
    for (int c = 1; c < N_CLASS_C; ++c) tmax = fmaxf(tmax, tc[c]);
    float s[N_CLASS_C];
#pragma unroll
    for (int c = 0; c < N_CLASS_C; ++c) s[c] = 0.0f;

    const int tid = blockIdx.x * blockDim.x + threadIdx.x;
    const int stride = gridDim.x * blockDim.x;
    for (int p = tid; p < n_pairs; p += stride) {
        int a0 = pairs[2 * p], a1 = pairs[2 * p + 1];
        float dx = coords[3 * a0] - coords[3 * a1];
        float dy = coords[3 * a0 + 1] - coords[3 * a1 + 1];
        float dz = coords[3 * a0 + 2] - coords[3 * a1 + 2];
        float dist = sqrtf(dx * dx + dy * dy + dz * dz + 1e-12f);
        float base = (radii[names[a0]] + radii[names[a1]]) - dist;
        if (base + tmax > 0.0f) {
#pragma unroll
            for (int c = 0; c < N_CLASS_C; ++c) {
                if (masks[(size_t)c * n_pairs + p])
                    s[c] += fmaxf(base + tc[c], 0.0f);
            }
        }
    }
    block_reduce_accum(s, accum);
}

__global__ void finalize_fb(const float* __restrict__ accum,
                            const float* __restrict__ w,
                            float* __restrict__ out) {
    int c = threadIdx.x;
    if (c < N_CLASS_C) {
        float scale = expf(w[0]);
        out[c] = accum[c] * scale;
    }
}

extern "C" void kernel_launch(void* const* d_in, const int* in_sizes, int n_in,
                              void* d_out, int out_size, void* d_ws, size_t ws_size,
                              hipStream_t stream) {
    const float* coords = (const float*)d_in[0];
    const float* radii  = (const float*)d_in[1];
    const float* tol    = (const float*)d_in[2];
    const float* weight = (const float*)d_in[3];
    const int* names    = (const int*)d_in[4];
    const int* pairs    = (const int*)d_in[5];
    const int* masks    = (const int*)d_in[6];
    float* out = (float*)d_out;

    int n_atoms = in_sizes[4];
    int n_radii = in_sizes[1];
    int n_pairs = in_sizes[5] / 2;

    int n_words = (n_atoms + 2) / 3;
    size_t atoms_off = 256;
    size_t atoms_bytes = (size_t)n_atoms * sizeof(HAtom);
    size_t cells_off = (atoms_off + atoms_bytes + 255) & ~(size_t)255;
    size_t need = cells_off + (size_t)n_words * 4 + 64;

    if (ws_size >= need && n_words <= MAX_WORDS) {
        float* accum = (float*)d_ws;                       // 6 floats
        unsigned* ticket = (unsigned*)((char*)d_ws + 24);
        HAtom* atoms = (HAtom*)((char*)d_ws + atoms_off);
        unsigned* cellsg = (unsigned*)((char*)d_ws + cells_off);

        zero_hdr<<<1, 64, 0, stream>>>(accum, ticket);
        prep<<<(n_words + 255) / 256, 256, 0, stream>>>(coords, radii, names, tol,
                                                        n_radii, atoms, cellsg,
                                                        n_words, n_atoms);
        clash_filtered<<<FILTER_GRID, FILTER_BLOCK, 0, stream>>>(
            pairs, atoms, cellsg, masks, tol, weight, accum, ticket, out,
            n_pairs, n_words, FILTER_GRID);
    } else {
        float* accum = out;
        zero_accum_fb<<<1, 64, 0, stream>>>(accum);
        clash_fallback<<<2048, 256, 0, stream>>>(pairs, coords, radii, names,
                                                 masks, tol, accum, n_pairs);
        finalize_fb<<<1, 64, 0, stream>>>(accum, weight, out);
    }
}

// Round 10
// 38.830 us; speedup vs baseline: 2.4819x; 2.4154x over previous
//
#include <hip/hip_runtime.h>
#include <hip/hip_fp16.h>

#define N_CLASS_C 6
#define MAX_WORDS 33344          // cell-table words; supports n_atoms <= 100,032
#define FILTER_BLOCK 1024
#define FILTER_GRID 256

typedef int vint2 __attribute__((ext_vector_type(2)));
typedef int vint4 __attribute__((ext_vector_type(4)));
typedef unsigned vuint4 __attribute__((ext_vector_type(4)));

// 8-byte packed atom record: fp16 x,y,z,radius. One dwordx2 gather per atom.
struct alignas(8) HAtom {
    __half x, y, z, r;
};

__global__ void zero_accum(float* accum) {
    if (threadIdx.x < N_CLASS_C) accum[threadIdx.x] = 0.0f;
}

// w = cell width = max possible clash distance (+margin), computed on device.
__global__ void compute_w(const float* __restrict__ radii, int n_radii,
                          const float* __restrict__ tol,
                          float* __restrict__ wval) {
    __shared__ float sh[4];
    float m = -1e30f;
    for (int i = threadIdx.x; i < n_radii; i += blockDim.x) m = fmaxf(m, radii[i]);
#pragma unroll
    for (int off = 32; off > 0; off >>= 1) m = fmaxf(m, __shfl_down(m, off, 64));
    if ((threadIdx.x & 63) == 0) sh[threadIdx.x >> 6] = m;
    __syncthreads();
    if (threadIdx.x == 0) {
        float mm = fmaxf(fmaxf(sh[0], sh[1]), fmaxf(sh[2], sh[3]));
        float tmax = -1e30f;
        for (int c = 0; c < N_CLASS_C; ++c) tmax = fmaxf(tmax, tol[c]);
        // any clash has dist < 2*rmax + tmax; margin for strictness
        wval[0] = fmaxf(2.0f * mm + tmax, 1e-2f) + 1e-3f;
    }
}

__global__ void prep_atoms(const float* __restrict__ coords,
                           const float* __restrict__ radii,
                           const int* __restrict__ names,
                           HAtom* __restrict__ atoms,
                           int n_atoms) {
    int i = blockIdx.x * blockDim.x + threadIdx.x;
    if (i < n_atoms) {
        HAtom a;
        a.x = __float2half(coords[3 * i + 0]);
        a.y = __float2half(coords[3 * i + 1]);
        a.z = __float2half(coords[3 * i + 2]);
        a.r = __float2half(radii[names[i]]);
        atoms[i] = a;
    }
}

// Per-atom 10-bit cell id: cx(3b) | cy(3b)<<3 | cz(4b)<<6, cell width w,
// clamped ranges x,y: [-4w,4w), z: [-8w,8w). 3 atoms packed per u32.
// Clamping only creates false positives (extra exact checks), never misses.
__global__ void prep_cells(const float* __restrict__ coords,
                           const float* __restrict__ wval,
                           unsigned* __restrict__ cellsg,
                           int n_words, int n_atoms) {
    float inv = 1.0f / wval[0];
    int t = blockIdx.x * blockDim.x + threadIdx.x;
    if (t < n_words) {
        unsigned word = 0;
#pragma unroll
        for (int s = 0; s < 3; ++s) {
            int i = 3 * t + s;
            unsigned c = 0;
            if (i < n_atoms) {
                float x = coords[3 * i + 0];
                float y = coords[3 * i + 1];
                float z = coords[3 * i + 2];
                int cx = (int)floorf(x * inv) + 4;
                int cy = (int)floorf(y * inv) + 4;
                int cz = (int)floorf(z * inv) + 8;
                cx = min(max(cx, 0), 7);
                cy = min(max(cy, 0), 7);
                cz = min(max(cz, 0), 15);
                c = (unsigned)cx | ((unsigned)cy << 3) | ((unsigned)cz << 6);
            }
            word |= c << (10 * s);
        }
        cellsg[t] = word;
    }
}

__device__ __forceinline__ unsigned cell_lookup(const unsigned* cells, int i) {
    // q = i / 3 (u32-safe magic), r = i % 3
    unsigned q = (unsigned)(((unsigned long long)(unsigned)i * 0xAAAAAAABull) >> 33);
    unsigned r = (unsigned)i - 3u * q;
    return (cells[q] >> (10u * r)) & 0x3FFu;
}

// Chebyshev cell distance test: true if all axis deltas <= 1.
__device__ __forceinline__ int cell_near(unsigned ca, unsigned cb) {
    int dx = abs((int)(ca & 7u) - (int)(cb & 7u));
    int dy = abs((int)((ca >> 3) & 7u) - (int)((cb >> 3) & 7u));
    int dz = abs((int)((ca >> 6) & 15u) - (int)((cb >> 6) & 15u));
    return (dx | dy | dz) <= 1;
}

__device__ __forceinline__ void block_reduce_accum(float* s, float* accum) {
    __shared__ float sh[N_CLASS_C];
    if (threadIdx.x < N_CLASS_C) sh[threadIdx.x] = 0.0f;
    __syncthreads();
#pragma unroll
    for (int c = 0; c < N_CLASS_C; ++c) {
        float v = s[c];
#pragma unroll
        for (int off = 32; off > 0; off >>= 1) v += __shfl_down(v, off, 64);
        if ((threadIdx.x & 63) == 0 && v != 0.0f) atomicAdd(&sh[c], v);
    }
    __syncthreads();
    if (threadIdx.x < N_CLASS_C) {
        float v = sh[threadIdx.x];
        if (v != 0.0f) atomicAdd(&accum[threadIdx.x], v);
    }
}

__device__ __forceinline__ float hdist_base(const HAtom& A, const HAtom& B) {
    float dx = __half2float(A.x) - __half2float(B.x);
    float dy = __half2float(A.y) - __half2float(B.y);
    float dz = __half2float(A.z) - __half2float(B.z);
    float dist = sqrtf(dx * dx + dy * dy + dz * dz + 1e-12f);
    return (__half2float(A.r) + __half2float(B.r)) - dist;
}

// Exact per-pair path for filter survivors (and the odd tail).
__device__ __forceinline__ void do_pair(
    int p, int a0, int a1,
    const HAtom* __restrict__ atoms, const int* __restrict__ masks,
    const float* tc, float tmax, float* s, int n_pairs) {
    HAtom A = atoms[a0];
    HAtom B = atoms[a1];
    float base = hdist_base(A, B);
    if (base + tmax > 0.0f) {
#pragma unroll
        for (int c = 0; c < N_CLASS_C; ++c) {
            if (masks[(size_t)c * n_pairs + p])
                s[c] += fmaxf(base + tc[c], 0.0f);
        }
    }
}

// Main kernel: LDS-resident cell table filters pairs without any VMEM
// request; only the surviving pairs issue the 2 scattered atom gathers.
// Processes 2 pairs per iteration (int4 load) for ILP/MLP.
__global__ __launch_bounds__(FILTER_BLOCK) void clash_filtered(
    const int* __restrict__ pairs,        // 2 * n_pairs
    const HAtom* __restrict__ atoms,
    const unsigned* __restrict__ cellsg,  // n_words packed cells
    const int* __restrict__ masks,        // N_CLASS * n_pairs
    const float* __restrict__ tol,
    float* __restrict__ accum,
    int n_pairs, int n_words) {
    __shared__ unsigned cells[MAX_WORDS];
    {
        const vuint4* src4 = reinterpret_cast<const vuint4*>(cellsg);
        int nw4 = n_words >> 2;
        for (int i = threadIdx.x; i < nw4; i += FILTER_BLOCK) {
            vuint4 v = src4[i];
            cells[4 * i + 0] = v.x;
            cells[4 * i + 1] = v.y;
            cells[4 * i + 2] = v.z;
            cells[4 * i + 3] = v.w;
        }
        for (int i = (nw4 << 2) + threadIdx.x; i < n_words; i += FILTER_BLOCK)
            cells[i] = cellsg[i];
    }

    float tc[N_CLASS_C];
#pragma unroll
    for (int c = 0; c < N_CLASS_C; ++c) tc[c] = tol[c];
    float tmax = tc[0];
#pragma unroll
    for (int c = 1; c < N_CLASS_C; ++c) tmax = fmaxf(tmax, tc[c]);

    float s[N_CLASS_C];
#pragma unroll
    for (int c = 0; c < N_CLASS_C; ++c) s[c] = 0.0f;

    __syncthreads();

    const vint4* pairs4 = reinterpret_cast<const vint4*>(pairs);  // 2 pairs/elt
    const int npair2 = n_pairs >> 1;
    const int stride = gridDim.x * FILTER_BLOCK;
    for (int q = blockIdx.x * FILTER_BLOCK + threadIdx.x; q < npair2; q += stride) {
        vint4 pq = pairs4[q];
        unsigned ca0 = cell_lookup(cells, pq.x);
        unsigned cb0 = cell_lookup(cells, pq.y);
        unsigned ca1 = cell_lookup(cells, pq.z);
        unsigned cb1 = cell_lookup(cells, pq.w);
        int hit0 = cell_near(ca0, cb0);
        int hit1 = cell_near(ca1, cb1);
        if (hit0) do_pair(2 * q, pq.x, pq.y, atoms, masks, tc, tmax, s, n_pairs);
        if (hit1) do_pair(2 * q + 1, pq.z, pq.w, atoms, masks, tc, tmax, s, n_pairs);
    }

    // Odd tail pair: exact path, one thread.
    if ((n_pairs & 1) && blockIdx.x == 0 && threadIdx.x == 0) {
        int p = n_pairs - 1;
        do_pair(p, pairs[2 * p], pairs[2 * p + 1], atoms, masks, tc, tmax, s, n_pairs);
    }

    block_reduce_accum(s, accum);
}

__global__ void finalize(const float* __restrict__ accum,
                         const float* __restrict__ w,
                         float* __restrict__ out) {
    int c = threadIdx.x;
    if (c < N_CLASS_C) {
        float scale = expf(w[0]);
        out[c] = accum[c] * scale;
    }
}

// -------- fallback (tiny ws / oversized atom count): direct gather path --------
__global__ __launch_bounds__(256) void clash_fallback(
    const int* __restrict__ pairs,
    const float* __restrict__ coords,
    const float* __restrict__ radii,
    const int* __restrict__ names,
    const int* __restrict__ masks,
    const float* __restrict__ tol,
    float* __restrict__ accum,
    int n_pairs) {
    float tc[N_CLASS_C];
#pragma unroll
    for (int c = 0; c < N_CLASS_C; ++c) tc[c] = tol[c];
    float tmax = tc[0];
#pragma unroll
    for (int c = 1; c < N_CLASS_C; ++c) tmax = fmaxf(tmax, tc[c]);
    float s[N_CLASS_C];
#pragma unroll
    for (int c = 0; c < N_CLASS_C; ++c) s[c] = 0.0f;

    const int tid = blockIdx.x * blockDim.x + threadIdx.x;
    const int stride = gridDim.x * blockDim.x;
    for (int p = tid; p < n_pairs; p += stride) {
        int a0 = pairs[2 * p], a1 = pairs[2 * p + 1];
        float dx = coords[3 * a0] - coords[3 * a1];
        float dy = coords[3 * a0 + 1] - coords[3 * a1 + 1];
        float dz = coords[3 * a0 + 2] - coords[3 * a1 + 2];
        float dist = sqrtf(dx * dx + dy * dy + dz * dz + 1e-12f);
        float base = (radii[names[a0]] + radii[names[a1]]) - dist;
        if (base + tmax > 0.0f) {
#pragma unroll
            for (int c = 0; c < N_CLASS_C; ++c) {
                if (masks[(size_t)c * n_pairs + p])
                    s[c] += fmaxf(base + tc[c], 0.0f);
            }
        }
    }
    block_reduce_accum(s, accum);
}

extern "C" void kernel_launch(void* const* d_in, const int* in_sizes, int n_in,
                              void* d_out, int out_size, void* d_ws, size_t ws_size,
                              hipStream_t stream) {
    const float* coords = (const float*)d_in[0];
    const float* radii  = (const float*)d_in[1];
    const float* tol    = (const float*)d_in[2];
    const float* weight = (const float*)d_in[3];
    const int* names    = (const int*)d_in[4];
    const int* pairs    = (const int*)d_in[5];
    const int* masks    = (const int*)d_in[6];
    float* out = (float*)d_out;

    int n_atoms = in_sizes[4];
    int n_radii = in_sizes[1];
    int n_pairs = in_sizes[5] / 2;

    int n_words = (n_atoms + 2) / 3;
    size_t atoms_off = 256;
    size_t atoms_bytes = (size_t)n_atoms * sizeof(HAtom);
    size_t cells_off = (atoms_off + atoms_bytes + 255) & ~(size_t)255;
    size_t need = cells_off + (size_t)n_words * 4 + 64;

    if (ws_size >= need && n_words <= MAX_WORDS) {
        float* accum = (float*)d_ws;                       // 6 floats
        float* wval  = (float*)((char*)d_ws + 32);         // 1 float
        HAtom* atoms = (HAtom*)((char*)d_ws + atoms_off);
        unsigned* cellsg = (unsigned*)((char*)d_ws + cells_off);

        compute_w<<<1, 256, 0, stream>>>(radii, n_radii, tol, wval);
        prep_atoms<<<(n_atoms + 255) / 256, 256, 0, stream>>>(coords, radii, names,
                                                              atoms, n_atoms);
        prep_cells<<<(n_words + 255) / 256, 256, 0, stream>>>(coords, wval,
                                                              cellsg, n_words, n_atoms);
        zero_accum<<<1, 64, 0, stream>>>(accum);
        clash_filtered<<<FILTER_GRID, FILTER_BLOCK, 0, stream>>>(
            pairs, atoms, cellsg, masks, tol, accum, n_pairs, n_words);
        finalize<<<1, 64, 0, stream>>>(accum, weight, out);
    } else {
        float* accum = out;
        zero_accum<<<1, 64, 0, stream>>>(accum);
        clash_fallback<<<2048, 256, 0, stream>>>(pairs, coords, radii, names,
                                                 masks, tol, accum, n_pairs);
        finalize<<<1, 64, 0, stream>>>(accum, weight, out);
    }
}

// Round 11
// 32.082 us; speedup vs baseline: 3.0039x; 1.2103x over previous
//
#include <hip/hip_runtime.h>
#include <hip/hip_fp16.h>

#define N_CLASS_C 6
#define MAX_WORDS 33344          // cell-table words; supports n_atoms <= 100,032
#define FILTER_BLOCK 1024
#define FILTER_GRID 256

typedef int vint2 __attribute__((ext_vector_type(2)));
typedef int vint4 __attribute__((ext_vector_type(4)));
typedef unsigned vuint4 __attribute__((ext_vector_type(4)));

// 8-byte packed atom record: fp16 x,y,z,radius. One dwordx2 gather per atom.
struct alignas(8) HAtom {
    __half x, y, z, r;
};

// ---------------- ws layout ----------------
// [0..24)   : accum[6]
// [256..)   : HAtom table
// then      : packed cell words (3 atoms / u32)

// Fused prep: per-block redundant w-reduce (radii max + tol max), then per
// word t: write 3 HAtom records + the packed cell word. Block 0 zeros accum.
// cell id: cx(3b) | cy(3b)<<3 | cz(4b)<<6, cell width w, clamped ranges
// x,y: [-4w,4w), z: [-8w,8w). Clamping only adds false positives (extra
// exact checks downstream), never false negatives.
__global__ __launch_bounds__(256) void prep(
    const float* __restrict__ coords,
    const float* __restrict__ radii,
    const int* __restrict__ names,
    const float* __restrict__ tol,
    int n_radii,
    HAtom* __restrict__ atoms,
    unsigned* __restrict__ cellsg,
    float* __restrict__ accum,
    int n_words, int n_atoms) {
    if (blockIdx.x == 0 && threadIdx.x < N_CLASS_C) accum[threadIdx.x] = 0.0f;

    __shared__ float sh[4];
    __shared__ float shw;
    {
        float m = 0.0f;
        for (int i = threadIdx.x; i < n_radii; i += blockDim.x)
            m = fmaxf(m, radii[i]);
#pragma unroll
        for (int off = 32; off > 0; off >>= 1) m = fmaxf(m, __shfl_down(m, off, 64));
        if ((threadIdx.x & 63) == 0) sh[threadIdx.x >> 6] = m;
        __syncthreads();
        if (threadIdx.x == 0) {
            float mm = fmaxf(fmaxf(sh[0], sh[1]), fmaxf(sh[2], sh[3]));
            float tmax = -1e30f;
            for (int c = 0; c < N_CLASS_C; ++c) tmax = fmaxf(tmax, tol[c]);
            // any clash has dist < 2*rmax + tmax; margin for strictness
            shw = fmaxf(2.0f * mm + tmax, 1e-2f) + 1e-3f;
        }
        __syncthreads();
    }
    float inv = 1.0f / shw;

    int t = blockIdx.x * blockDim.x + threadIdx.x;
    if (t < n_words) {
        unsigned word = 0;
#pragma unroll
        for (int s = 0; s < 3; ++s) {
            int i = 3 * t + s;
            unsigned c = 0;
            if (i < n_atoms) {
                float x = coords[3 * i + 0];
                float y = coords[3 * i + 1];
                float z = coords[3 * i + 2];
                HAtom a;
                a.x = __float2half(x);
                a.y = __float2half(y);
                a.z = __float2half(z);
                a.r = __float2half(radii[names[i]]);
                atoms[i] = a;
                int cx = (int)floorf(x * inv) + 4;
                int cy = (int)floorf(y * inv) + 4;
                int cz = (int)floorf(z * inv) + 8;
                cx = min(max(cx, 0), 7);
                cy = min(max(cy, 0), 7);
                cz = min(max(cz, 0), 15);
                c = (unsigned)cx | ((unsigned)cy << 3) | ((unsigned)cz << 6);
            }
            word |= c << (10 * s);
        }
        cellsg[t] = word;
    }
}

__device__ __forceinline__ unsigned cell_lookup(const unsigned* cells, int i) {
    // q = i / 3 (u32-safe magic), r = i % 3
    unsigned q = (unsigned)(((unsigned long long)(unsigned)i * 0xAAAAAAABull) >> 33);
    unsigned r = (unsigned)i - 3u * q;
    return (cells[q] >> (10u * r)) & 0x3FFu;
}

// Chebyshev cell distance test: true if all axis deltas <= 1.
__device__ __forceinline__ int cell_near(unsigned ca, unsigned cb) {
    int dx = abs((int)(ca & 7u) - (int)(cb & 7u));
    int dy = abs((int)((ca >> 3) & 7u) - (int)((cb >> 3) & 7u));
    int dz = abs((int)((ca >> 6) & 15u) - (int)((cb >> 6) & 15u));
    return (dx | dy | dz) <= 1;
}

__device__ __forceinline__ void block_reduce_accum(float* s, float* accum) {
    __shared__ float sh[N_CLASS_C];
    if (threadIdx.x < N_CLASS_C) sh[threadIdx.x] = 0.0f;
    __syncthreads();
#pragma unroll
    for (int c = 0; c < N_CLASS_C; ++c) {
        float v = s[c];
#pragma unroll
        for (int off = 32; off > 0; off >>= 1) v += __shfl_down(v, off, 64);
        if ((threadIdx.x & 63) == 0 && v != 0.0f) atomicAdd(&sh[c], v);
    }
    __syncthreads();
    if (threadIdx.x < N_CLASS_C) {
        float v = sh[threadIdx.x];
        if (v != 0.0f) atomicAdd(&accum[threadIdx.x], v);
    }
}

__device__ __forceinline__ float hdist_base(const HAtom& A, const HAtom& B) {
    float dx = __half2float(A.x) - __half2float(B.x);
    float dy = __half2float(A.y) - __half2float(B.y);
    float dz = __half2float(A.z) - __half2float(B.z);
    float dist = sqrtf(dx * dx + dy * dy + dz * dz + 1e-12f);
    return (__half2float(A.r) + __half2float(B.r)) - dist;
}

// Exact per-pair path for filter survivors (and the odd tail).
__device__ __forceinline__ void do_pair(
    int p, int a0, int a1,
    const HAtom* __restrict__ atoms, const int* __restrict__ masks,
    const float* tc, float tmax, float* s, int n_pairs) {
    HAtom A = atoms[a0];
    HAtom B = atoms[a1];
    float base = hdist_base(A, B);
    if (base + tmax > 0.0f) {
#pragma unroll
        for (int c = 0; c < N_CLASS_C; ++c) {
            if (masks[(size_t)c * n_pairs + p])
                s[c] += fmaxf(base + tc[c], 0.0f);
        }
    }
}

// Main kernel: LDS-resident cell table filters pairs without any VMEM
// request; only the surviving pairs issue the 2 scattered atom gathers.
// Processes 2 pairs per iteration (int4 load) for ILP/MLP.
// NOTE: keep this kernel free of device-scope fences / ticket epilogues —
// adding them measured a 3x whole-kernel slowdown (rounds 8-9).
__global__ __launch_bounds__(FILTER_BLOCK) void clash_filtered(
    const int* __restrict__ pairs,        // 2 * n_pairs
    const HAtom* __restrict__ atoms,
    const unsigned* __restrict__ cellsg,  // n_words packed cells
    const int* __restrict__ masks,        // N_CLASS * n_pairs
    const float* __restrict__ tol,
    float* __restrict__ accum,
    int n_pairs, int n_words) {
    __shared__ unsigned cells[MAX_WORDS];
    {
        const vuint4* src4 = reinterpret_cast<const vuint4*>(cellsg);
        int nw4 = n_words >> 2;
        for (int i = threadIdx.x; i < nw4; i += FILTER_BLOCK) {
            vuint4 v = src4[i];
            cells[4 * i + 0] = v.x;
            cells[4 * i + 1] = v.y;
            cells[4 * i + 2] = v.z;
            cells[4 * i + 3] = v.w;
        }
        for (int i = (nw4 << 2) + threadIdx.x; i < n_words; i += FILTER_BLOCK)
            cells[i] = cellsg[i];
    }

    float tc[N_CLASS_C];
#pragma unroll
    for (int c = 0; c < N_CLASS_C; ++c) tc[c] = tol[c];
    float tmax = tc[0];
#pragma unroll
    for (int c = 1; c < N_CLASS_C; ++c) tmax = fmaxf(tmax, tc[c]);

    float s[N_CLASS_C];
#pragma unroll
    for (int c = 0; c < N_CLASS_C; ++c) s[c] = 0.0f;

    __syncthreads();

    const vint4* pairs4 = reinterpret_cast<const vint4*>(pairs);  // 2 pairs/elt
    const int npair2 = n_pairs >> 1;
    const int stride = gridDim.x * FILTER_BLOCK;
    for (int q = blockIdx.x * FILTER_BLOCK + threadIdx.x; q < npair2; q += stride) {
        vint4 pq = pairs4[q];
        unsigned ca0 = cell_lookup(cells, pq.x);
        unsigned cb0 = cell_lookup(cells, pq.y);
        unsigned ca1 = cell_lookup(cells, pq.z);
        unsigned cb1 = cell_lookup(cells, pq.w);
        int hit0 = cell_near(ca0, cb0);
        int hit1 = cell_near(ca1, cb1);
        if (hit0) do_pair(2 * q, pq.x, pq.y, atoms, masks, tc, tmax, s, n_pairs);
        if (hit1) do_pair(2 * q + 1, pq.z, pq.w, atoms, masks, tc, tmax, s, n_pairs);
    }

    // Odd tail pair: exact path, one thread.
    if ((n_pairs & 1) && blockIdx.x == 0 && threadIdx.x == 0) {
        int p = n_pairs - 1;
        do_pair(p, pairs[2 * p], pairs[2 * p + 1], atoms, masks, tc, tmax, s, n_pairs);
    }

    block_reduce_accum(s, accum);
}

__global__ void finalize(const float* __restrict__ accum,
                         const float* __restrict__ w,
                         float* __restrict__ out) {
    int c = threadIdx.x;
    if (c < N_CLASS_C) {
        float scale = expf(w[0]);
        out[c] = accum[c] * scale;
    }
}

// -------- fallback (tiny ws / oversized atom count): direct gather path --------
__global__ void zero_accum_fb(float* accum) {
    if (threadIdx.x < N_CLASS_C) accum[threadIdx.x] = 0.0f;
}

__global__ __launch_bounds__(256) void clash_fallback(
    const int* __restrict__ pairs,
    const float* __restrict__ coords,
    const float* __restrict__ radii,
    const int* __restrict__ names,
    const int* __restrict__ masks,
    const float* __restrict__ tol,
    float* __restrict__ accum,
    int n_pairs) {
    float tc[N_CLASS_C];
#pragma unroll
    for (int c = 0; c < N_CLASS_C; ++c) tc[c] = tol[c];
    float tmax = tc[0];
#pragma unroll
    for (int c = 1; c < N_CLASS_C; ++c) tmax = fmaxf(tmax, tc[c]);
    float s[N_CLASS_C];
#pragma unroll
    for (int c = 0; c < N_CLASS_C; ++c) s[c] = 0.0f;

    const int tid = blockIdx.x * blockDim.x + threadIdx.x;
    const int stride = gridDim.x * blockDim.x;
    for (int p = tid; p < n_pairs; p += stride) {
        int a0 = pairs[2 * p], a1 = pairs[2 * p + 1];
        float dx = coords[3 * a0] - coords[3 * a1];
        float dy = coords[3 * a0 + 1] - coords[3 * a1 + 1];
        float dz = coords[3 * a0 + 2] - coords[3 * a1 + 2];
        float dist = sqrtf(dx * dx + dy * dy + dz * dz + 1e-12f);
        float base = (radii[names[a0]] + radii[names[a1]]) - dist;
        if (base + tmax > 0.0f) {
#pragma unroll
            for (int c = 0; c < N_CLASS_C; ++c) {
                if (masks[(size_t)c * n_pairs + p])
                    s[c] += fmaxf(base + tc[c], 0.0f);
            }
        }
    }
    block_reduce_accum(s, accum);
}

extern "C" void kernel_launch(void* const* d_in, const int* in_sizes, int n_in,
                              void* d_out, int out_size, void* d_ws, size_t ws_size,
                              hipStream_t stream) {
    const float* coords = (const float*)d_in[0];
    const float* radii  = (const float*)d_in[1];
    const float* tol    = (const float*)d_in[2];
    const float* weight = (const float*)d_in[3];
    const int* names    = (const int*)d_in[4];
    const int* pairs    = (const int*)d_in[5];
    const int* masks    = (const int*)d_in[6];
    float* out = (float*)d_out;

    int n_atoms = in_sizes[4];
    int n_radii = in_sizes[1];
    int n_pairs = in_sizes[5] / 2;

    int n_words = (n_atoms + 2) / 3;
    size_t atoms_off = 256;
    size_t atoms_bytes = (size_t)n_atoms * sizeof(HAtom);
    size_t cells_off = (atoms_off + atoms_bytes + 255) & ~(size_t)255;
    size_t need = cells_off + (size_t)n_words * 4 + 64;

    if (ws_size >= need && n_words <= MAX_WORDS) {
        float* accum = (float*)d_ws;                       // 6 floats
        HAtom* atoms = (HAtom*)((char*)d_ws + atoms_off);
        unsigned* cellsg = (unsigned*)((char*)d_ws + cells_off);

        prep<<<(n_words + 255) / 256, 256, 0, stream>>>(
            coords, radii, names, tol, n_radii, atoms, cellsg, accum,
            n_words, n_atoms);
        clash_filtered<<<FILTER_GRID, FILTER_BLOCK, 0, stream>>>(
            pairs, atoms, cellsg, masks, tol, accum, n_pairs, n_words);
        finalize<<<1, 64, 0, stream>>>(accum, weight, out);
    } else {
        float* accum = out;
        zero_accum_fb<<<1, 64, 0, stream>>>(accum);
        clash_fallback<<<2048, 256, 0, stream>>>(pairs, coords, radii, names,
                                                 masks, tol, accum, n_pairs);
        finalize<<<1, 64, 0, stream>>>(accum, weight, out);
    }
}

// Round 12
// 31.302 us; speedup vs baseline: 3.0788x; 1.0249x over previous
//
#include <hip/hip_runtime.h>
#include <hip/hip_fp16.h>

#define N_CLASS_C 6
#define MAX_WORDS 33344          // cell-table words; supports n_atoms <= 100,032
#define FILTER_BLOCK 1024
#define FILTER_GRID 256

typedef int vint4 __attribute__((ext_vector_type(4)));
typedef unsigned vuint4 __attribute__((ext_vector_type(4)));

// 8-byte packed atom record: fp16 x,y,z,radius. One dwordx2 gather per atom.
struct alignas(8) HAtom {
    __half x, y, z, r;
};

// ---------------- ws layout ----------------
// [256..)   : HAtom table
// then      : packed cell words (3 atoms / u32)

// Fused prep: per-block redundant w-reduce (radii max + tol max), then per
// word t: write 3 HAtom records + the packed cell word. Block 0 zeros d_out
// (filter blocks accumulate into d_out directly; stream order guarantees
// prep completes first — no fence needed).
// cell id: cx(3b) | cy(3b)<<3 | cz(4b)<<6, cell width w, clamped ranges
// x,y: [-4w,4w), z: [-8w,8w). Clamping only adds false positives (extra
// exact checks downstream), never false negatives.
__global__ __launch_bounds__(256) void prep(
    const float* __restrict__ coords,
    const float* __restrict__ radii,
    const int* __restrict__ names,
    const float* __restrict__ tol,
    int n_radii,
    HAtom* __restrict__ atoms,
    unsigned* __restrict__ cellsg,
    float* __restrict__ out,
    int n_words, int n_atoms) {
    if (blockIdx.x == 0 && threadIdx.x < N_CLASS_C) out[threadIdx.x] = 0.0f;

    __shared__ float sh[4];
    __shared__ float shw;
    {
        float m = 0.0f;
        for (int i = threadIdx.x; i < n_radii; i += blockDim.x)
            m = fmaxf(m, radii[i]);
#pragma unroll
        for (int off = 32; off > 0; off >>= 1) m = fmaxf(m, __shfl_down(m, off, 64));
        if ((threadIdx.x & 63) == 0) sh[threadIdx.x >> 6] = m;
        __syncthreads();
        if (threadIdx.x == 0) {
            float mm = fmaxf(fmaxf(sh[0], sh[1]), fmaxf(sh[2], sh[3]));
            float tmax = -1e30f;
            for (int c = 0; c < N_CLASS_C; ++c) tmax = fmaxf(tmax, tol[c]);
            // any clash has dist < 2*rmax + tmax; margin for strictness
            shw = fmaxf(2.0f * mm + tmax, 1e-2f) + 1e-3f;
        }
        __syncthreads();
    }
    float inv = 1.0f / shw;

    int t = blockIdx.x * blockDim.x + threadIdx.x;
    if (t < n_words) {
        unsigned word = 0;
#pragma unroll
        for (int s = 0; s < 3; ++s) {
            int i = 3 * t + s;
            unsigned c = 0;
            if (i < n_atoms) {
                float x = coords[3 * i + 0];
                float y = coords[3 * i + 1];
                float z = coords[3 * i + 2];
                HAtom a;
                a.x = __float2half(x);
                a.y = __float2half(y);
                a.z = __float2half(z);
                a.r = __float2half(radii[names[i]]);
                atoms[i] = a;
                int cx = (int)floorf(x * inv) + 4;
                int cy = (int)floorf(y * inv) + 4;
                int cz = (int)floorf(z * inv) + 8;
                cx = min(max(cx, 0), 7);
                cy = min(max(cy, 0), 7);
                cz = min(max(cz, 0), 15);
                c = (unsigned)cx | ((unsigned)cy << 3) | ((unsigned)cz << 6);
            }
            word |= c << (10 * s);
        }
        cellsg[t] = word;
    }
}

__device__ __forceinline__ unsigned cell_lookup(const unsigned* cells, int i) {
    // q = i / 3 (u32-safe magic), r = i % 3
    unsigned q = (unsigned)(((unsigned long long)(unsigned)i * 0xAAAAAAABull) >> 33);
    unsigned r = (unsigned)i - 3u * q;
    return (cells[q] >> (10u * r)) & 0x3FFu;
}

// Chebyshev cell distance test: true if all axis deltas <= 1.
__device__ __forceinline__ int cell_near(unsigned ca, unsigned cb) {
    int dx = abs((int)(ca & 7u) - (int)(cb & 7u));
    int dy = abs((int)((ca >> 3) & 7u) - (int)((cb >> 3) & 7u));
    int dz = abs((int)((ca >> 6) & 15u) - (int)((cb >> 6) & 15u));
    return (dx | dy | dz) <= 1;
}

__device__ __forceinline__ float hdist_base(const HAtom& A, const HAtom& B) {
    float dx = __half2float(A.x) - __half2float(B.x);
    float dy = __half2float(A.y) - __half2float(B.y);
    float dz = __half2float(A.z) - __half2float(B.z);
    float dist = sqrtf(dx * dx + dy * dy + dz * dz + 1e-12f);
    return (__half2float(A.r) + __half2float(B.r)) - dist;
}

// Exact per-pair path for filter survivors (and the odd tail).
__device__ __forceinline__ void do_pair(
    int p, int a0, int a1,
    const HAtom* __restrict__ atoms, const int* __restrict__ masks,
    const float* tc, float tmax, float* s, int n_pairs) {
    HAtom A = atoms[a0];
    HAtom B = atoms[a1];
    float base = hdist_base(A, B);
    if (base + tmax > 0.0f) {
#pragma unroll
        for (int c = 0; c < N_CLASS_C; ++c) {
            if (masks[(size_t)c * n_pairs + p])
                s[c] += fmaxf(base + tc[c], 0.0f);
        }
    }
}

// Main kernel: LDS-resident cell table filters pairs without any VMEM
// request; only the surviving pairs issue the 2 scattered atom gathers.
// Processes 2 pairs per iteration (int4 load) for ILP/MLP.
// Epilogue: block partials are scaled by exp(weight) and atomically added
// straight into d_out (prep zeroed it; stream order = sync). NOTE: keep this
// kernel free of device-scope fences / ticket epilogues — those measured a
// 3x whole-kernel slowdown (rounds 8-9 vs 10-11).
__global__ __launch_bounds__(FILTER_BLOCK) void clash_filtered(
    const int* __restrict__ pairs,        // 2 * n_pairs
    const HAtom* __restrict__ atoms,
    const unsigned* __restrict__ cellsg,  // n_words packed cells
    const int* __restrict__ masks,        // N_CLASS * n_pairs
    const float* __restrict__ tol,
    const float* __restrict__ weight,
    float* __restrict__ out,
    int n_pairs, int n_words) {
    __shared__ unsigned cells[MAX_WORDS];
    {
        const vuint4* src4 = reinterpret_cast<const vuint4*>(cellsg);
        int nw4 = n_words >> 2;
        for (int i = threadIdx.x; i < nw4; i += FILTER_BLOCK) {
            vuint4 v = src4[i];
            cells[4 * i + 0] = v.x;
            cells[4 * i + 1] = v.y;
            cells[4 * i + 2] = v.z;
            cells[4 * i + 3] = v.w;
        }
        for (int i = (nw4 << 2) + threadIdx.x; i < n_words; i += FILTER_BLOCK)
            cells[i] = cellsg[i];
    }

    float tc[N_CLASS_C];
#pragma unroll
    for (int c = 0; c < N_CLASS_C; ++c) tc[c] = tol[c];
    float tmax = tc[0];
#pragma unroll
    for (int c = 1; c < N_CLASS_C; ++c) tmax = fmaxf(tmax, tc[c]);

    float s[N_CLASS_C];
#pragma unroll
    for (int c = 0; c < N_CLASS_C; ++c) s[c] = 0.0f;

    __syncthreads();

    const vint4* pairs4 = reinterpret_cast<const vint4*>(pairs);  // 2 pairs/elt
    const int npair2 = n_pairs >> 1;
    const int stride = gridDim.x * FILTER_BLOCK;
    for (int q = blockIdx.x * FILTER_BLOCK + threadIdx.x; q < npair2; q += stride) {
        vint4 pq = pairs4[q];
        unsigned ca0 = cell_lookup(cells, pq.x);
        unsigned cb0 = cell_lookup(cells, pq.y);
        unsigned ca1 = cell_lookup(cells, pq.z);
        unsigned cb1 = cell_lookup(cells, pq.w);
        int hit0 = cell_near(ca0, cb0);
        int hit1 = cell_near(ca1, cb1);
        if (hit0) do_pair(2 * q, pq.x, pq.y, atoms, masks, tc, tmax, s, n_pairs);
        if (hit1) do_pair(2 * q + 1, pq.z, pq.w, atoms, masks, tc, tmax, s, n_pairs);
    }

    // Odd tail pair: exact path, one thread.
    if ((n_pairs & 1) && blockIdx.x == 0 && threadIdx.x == 0) {
        int p = n_pairs - 1;
        do_pair(p, pairs[2 * p], pairs[2 * p + 1], atoms, masks, tc, tmax, s, n_pairs);
    }

    // Block reduce, then scale by exp(weight) and add into d_out.
    __shared__ float shsum[N_CLASS_C];
    if (threadIdx.x < N_CLASS_C) shsum[threadIdx.x] = 0.0f;
    __syncthreads();
#pragma unroll
    for (int c = 0; c < N_CLASS_C; ++c) {
        float v = s[c];
#pragma unroll
        for (int off = 32; off > 0; off >>= 1) v += __shfl_down(v, off, 64);
        if ((threadIdx.x & 63) == 0 && v != 0.0f) atomicAdd(&shsum[c], v);
    }
    __syncthreads();
    if (threadIdx.x < N_CLASS_C) {
        float expw = expf(weight[0]);
        atomicAdd(&out[threadIdx.x], shsum[threadIdx.x] * expw);
    }
}

// -------- fallback (tiny ws / oversized atom count): direct gather path --------
__global__ void zero_accum_fb(float* accum) {
    if (threadIdx.x < N_CLASS_C) accum[threadIdx.x] = 0.0f;
}

__device__ __forceinline__ void block_reduce_accum_fb(float* s, float* accum) {
    __shared__ float sh[N_CLASS_C];
    if (threadIdx.x < N_CLASS_C) sh[threadIdx.x] = 0.0f;
    __syncthreads();
#pragma unroll
    for (int c = 0; c < N_CLASS_C; ++c) {
        float v = s[c];
#pragma unroll
        for (int off = 32; off > 0; off >>= 1) v += __shfl_down(v, off, 64);
        if ((threadIdx.x & 63) == 0 && v != 0.0f) atomicAdd(&sh[c], v);
    }
    __syncthreads();
    if (threadIdx.x < N_CLASS_C) {
        float v = sh[threadIdx.x];
        if (v != 0.0f) atomicAdd(&accum[threadIdx.x], v);
    }
}

__global__ __launch_bounds__(256) void clash_fallback(
    const int* __restrict__ pairs,
    const float* __restrict__ coords,
    const float* __restrict__ radii,
    const int* __restrict__ names,
    const int* __restrict__ masks,
    const float* __restrict__ tol,
    float* __restrict__ accum,
    int n_pairs) {
    float tc[N_CLASS_C];
#pragma unroll
    for (int c = 0; c < N_CLASS_C; ++c) tc[c] = tol[c];
    float tmax = tc[0];
#pragma unroll
    for (int c = 1; c < N_CLASS_C; ++c) tmax = fmaxf(tmax, tc[c]);
    float s[N_CLASS_C];
#pragma unroll
    for (int c = 0; c < N_CLASS_C; ++c) s[c] = 0.0f;

    const int tid = blockIdx.x * blockDim.x + threadIdx.x;
    const int stride = gridDim.x * blockDim.x;
    for (int p = tid; p < n_pairs; p += stride) {
        int a0 = pairs[2 * p], a1 = pairs[2 * p + 1];
        float dx = coords[3 * a0] - coords[3 * a1];
        float dy = coords[3 * a0 + 1] - coords[3 * a1 + 1];
        float dz = coords[3 * a0 + 2] - coords[3 * a1 + 2];
        float dist = sqrtf(dx * dx + dy * dy + dz * dz + 1e-12f);
        float base = (radii[names[a0]] + radii[names[a1]]) - dist;
        if (base + tmax > 0.0f) {
#pragma unroll
            for (int c = 0; c < N_CLASS_C; ++c) {
                if (masks[(size_t)c * n_pairs + p])
                    s[c] += fmaxf(base + tc[c], 0.0f);
            }
        }
    }
    block_reduce_accum_fb(s, accum);
}

__global__ void finalize_fb(const float* __restrict__ accum,
                            const float* __restrict__ w,
                            float* __restrict__ out) {
    int c = threadIdx.x;
    if (c < N_CLASS_C) {
        float scale = expf(w[0]);
        out[c] = accum[c] * scale;
    }
}

extern "C" void kernel_launch(void* const* d_in, const int* in_sizes, int n_in,
                              void* d_out, int out_size, void* d_ws, size_t ws_size,
                              hipStream_t stream) {
    const float* coords = (const float*)d_in[0];
    const float* radii  = (const float*)d_in[1];
    const float* tol    = (const float*)d_in[2];
    const float* weight = (const float*)d_in[3];
    const int* names    = (const int*)d_in[4];
    const int* pairs    = (const int*)d_in[5];
    const int* masks    = (const int*)d_in[6];
    float* out = (float*)d_out;

    int n_atoms = in_sizes[4];
    int n_radii = in_sizes[1];
    int n_pairs = in_sizes[5] / 2;

    int n_words = (n_atoms + 2) / 3;
    size_t atoms_off = 256;
    size_t atoms_bytes = (size_t)n_atoms * sizeof(HAtom);
    size_t cells_off = (atoms_off + atoms_bytes + 255) & ~(size_t)255;
    size_t need = cells_off + (size_t)n_words * 4 + 64;

    if (ws_size >= need && n_words <= MAX_WORDS) {
        HAtom* atoms = (HAtom*)((char*)d_ws + atoms_off);
        unsigned* cellsg = (unsigned*)((char*)d_ws + cells_off);

        prep<<<(n_words + 255) / 256, 256, 0, stream>>>(
            coords, radii, names, tol, n_radii, atoms, cellsg, out,
            n_words, n_atoms);
        clash_filtered<<<FILTER_GRID, FILTER_BLOCK, 0, stream>>>(
            pairs, atoms, cellsg, masks, tol, weight, out, n_pairs, n_words);
    } else {
        float* accum = out;
        zero_accum_fb<<<1, 64, 0, stream>>>(accum);
        clash_fallback<<<2048, 256, 0, stream>>>(pairs, coords, radii, names,
                                                 masks, tol, accum, n_pairs);
        finalize_fb<<<1, 64, 0, stream>>>(accum, weight, out);
    }
}